// Round 23
// baseline (207.579 us; speedup 1.0000x reference)
//
#include <hip/hip_runtime.h>
#include <stdint.h>

// PointNet SA via MFMA, v18 = v13 dataflow with FAT WAVES: 64 pts / 256 thr /
// 4 waves / 48KB LDS -> 3 blocks/CU. Each wave owns a full o-tile x ALL 4
// p-tiles (NPT=4): 4-16 independent accumulator chains per stage (vs 2) hides
// the ~32cy MFMA dependency latency that 16 barrier-aligned thin waves could
// not. Weight loads amortized 2x per point; barrier tail halved. Same verified
// fragment maps, rounding chains (absmax invariant), cvt_pk packing.

namespace {
constexpr int kB = 4, kN = 16384, kC = 103, kP = 2048, kS = 32;

using short8 = __attribute__((ext_vector_type(8))) short;
using short4 = __attribute__((ext_vector_type(4))) short;
using f32x4  = __attribute__((ext_vector_type(4))) float;

constexpr int WG_HI = 0,     WG_LO = 8192;     // 64 x 128
constexpr int W1_HI = 16384, W1_LO = 20480;    // 64 x 64
constexpr int W2_HI = 24576, W2_LO = 32768;    // 128 x 64
constexpr int W3_HI = 40960, W3_LO = 73728;    // 256 x 128
constexpr size_t FT_OFF    = 262144;
constexpr size_t FT_SHORTS = (size_t)kB * kN * 128;
constexpr size_t WS_NEED   = FT_OFF + 2 * FT_SHORTS * 2;

__device__ __forceinline__ unsigned short f2bf(float x) {
    unsigned u = __float_as_uint(x);
    u += 0x7fffu + ((u >> 16) & 1u);           // RNE
    return (unsigned short)(u >> 16);
}
__device__ __forceinline__ float bf2f(unsigned short h) {
    return __uint_as_float((unsigned)h << 16);
}
__device__ __forceinline__ unsigned cvtpk(float a, float b) {
    unsigned r;
    asm("v_cvt_pk_bf16_f32 %0, %1, %2" : "=v"(r) : "v"(a), "v"(b));
    return r;
}
__device__ __forceinline__ void pack4(const float v[4], uint2& H, uint2& L) {
    H.x = cvtpk(v[0], v[1]);
    H.y = cvtpk(v[2], v[3]);
    const float r0 = v[0] - __uint_as_float(H.x << 16);
    const float r1 = v[1] - __uint_as_float(H.x & 0xffff0000u);
    const float r2 = v[2] - __uint_as_float(H.y << 16);
    const float r3 = v[3] - __uint_as_float(H.y & 0xffff0000u);
    L.x = cvtpk(r0, r1);
    L.y = cvtpk(r2, r3);
}
__device__ __forceinline__ f32x4 mfma3(short8 ah, short8 al, short8 bh, short8 bl, f32x4 acc) {
    acc = __builtin_amdgcn_mfma_f32_16x16x32_bf16(ah, bh, acc, 0, 0, 0);
    acc = __builtin_amdgcn_mfma_f32_16x16x32_bf16(ah, bl, acc, 0, 0, 0);
    acc = __builtin_amdgcn_mfma_f32_16x16x32_bf16(al, bh, acc, 0, 0, 0);
    return acc;
}

__global__ void copy_newxyz(const float* __restrict__ src, float* __restrict__ dst, int n) {
    int i = blockIdx.x * blockDim.x + threadIdx.x;
    if (i < n) dst[i] = src[i];
}

__global__ void prep_weights(const float* __restrict__ Wg, const float* __restrict__ W1,
                             const float* __restrict__ W2, const float* __restrict__ W3,
                             short* __restrict__ ws) {
    int i = blockIdx.x * blockDim.x + threadIdx.x;
    if (i >= 53248) return;
    float w; int hi, lo, j;
    if (i < 8192)       { j = i;         int o = j >> 7, c = j & 127; w = (c < 106) ? Wg[o * 106 + c] : 0.f; hi = WG_HI; lo = WG_LO; }
    else if (i < 12288) { j = i - 8192;  int o = j >> 6, c = j & 63;  w = W1[o * 64 + c];  hi = W1_HI; lo = W1_LO; }
    else if (i < 20480) { j = i - 12288; int o = j >> 6, c = j & 63;  w = W2[o * 64 + c];  hi = W2_HI; lo = W2_LO; }
    else                { j = i - 20480; int o = j >> 7, c = j & 127; w = W3[o * 128 + c]; hi = W3_HI; lo = W3_LO; }
    unsigned short h = f2bf(w);
    ws[hi + j] = (short)h;
    ws[lo + j] = (short)f2bf(w - bf2f(h));
}

__global__ __launch_bounds__(512) void prep_feat(const float* __restrict__ f,
                                                 short* __restrict__ ftH, short* __restrict__ ftL) {
    __shared__ float tile[kC][65];
    const int bb = blockIdx.x >> 8;
    const int n0 = (blockIdx.x & 255) * 64;
    const int tid = threadIdx.x;
    for (int c = tid >> 6; c < kC; c += 8)
        tile[c][tid & 63] = f[((size_t)bb * kC + c) * kN + n0 + (tid & 63)];
    __syncthreads();
    const int np = tid >> 3, gc = tid & 7;
    short* rH = ftH + ((size_t)bb * kN + n0 + np) * 128;
    short* rL = ftL + ((size_t)bb * kN + n0 + np) * 128;
    #pragma unroll
    for (int kk = 0; kk < 2; ++kk) {
        const int chunk = gc + 8 * kk;
        union { uint4 u; short s[8]; } H, L;
        #pragma unroll
        for (int e = 0; e < 8; ++e) {
            const int col = chunk * 8 + e;
            float v = (col >= 3 && col < 106) ? tile[col - 3][np] : 0.f;
            unsigned short hh = f2bf(v);
            H.s[e] = (short)hh;
            L.s[e] = (short)f2bf(v - bf2f(hh));
        }
        *(uint4*)(rH + chunk * 8) = H.u;
        *(uint4*)(rL + chunk * 8) = L.u;
    }
}

// A: m=lane&15 (W row), k=8*(lane>>4)+j; B: n=lane&15 (point), same k; D: n=lane&15, m=4*(lane>>4)+r
template<int NOT, int NPT, int KT, int LDC, int LDW, bool INIT>
__device__ __forceinline__ void gemm_core(
    const short* __restrict__ xh, const short* __restrict__ xl,
    const short* __restrict__ wh, const short* __restrict__ wl,
    const float* __restrict__ bias, int kwoff,
    int ot0, int pt0t, int lane, f32x4 (&acc)[NOT][NPT])
{
    const int q = lane >> 4, n16 = lane & 15;
    if constexpr (INIT) {
        #pragma unroll
        for (int i = 0; i < NOT; ++i) {
            const f32x4 binit = *(const f32x4*)(bias + (ot0 + i) * 16 + 4 * q);
            #pragma unroll
            for (int j = 0; j < NPT; ++j) acc[i][j] = binit;
        }
    }
    #pragma unroll
    for (int kt = 0; kt < KT; ++kt) {
        const int k0 = kt * 32 + q * 8;
        short8 bh[NPT], bl[NPT];
        #pragma unroll
        for (int j = 0; j < NPT; ++j) {
            const int p = (pt0t + j) * 16 + n16;
            const int e = p * LDC + (k0 ^ ((p & 7) << 3));
            bh[j] = *(const short8*)(xh + e);
            bl[j] = *(const short8*)(xl + e);
        }
        #pragma unroll
        for (int i = 0; i < NOT; ++i) {
            const size_t we = (size_t)((ot0 + i) * 16 + n16) * LDW + kwoff + k0;
            const short8 ah = *(const short8*)(wh + we);
            const short8 al = *(const short8*)(wl + we);
            #pragma unroll
            for (int j = 0; j < NPT; ++j) acc[i][j] = mfma3(ah, al, bh[j], bl[j], acc[i][j]);
        }
    }
}

// GATE: v = base*(1+acc) with base from NF planes; else relu. cvt_pk packing.
template<int NOT, int NPT, bool GATE, int LDCO>
__device__ __forceinline__ void store_act(
    f32x4 (&acc)[NOT][NPT], short* __restrict__ oh, short* __restrict__ ol,
    const short* __restrict__ nfh, const short* __restrict__ nfl,
    int ot0, int pt0t, int lane)
{
    const int q = lane >> 4, n16 = lane & 15;
    #pragma unroll
    for (int i = 0; i < NOT; ++i) {
        const int ob = (ot0 + i) * 16 + 4 * q;
        #pragma unroll
        for (int j = 0; j < NPT; ++j) {
            const int p = (pt0t + j) * 16 + n16;
            const int cs = ob ^ ((p & 7) << 3);
            float v[4];
            if (GATE) {
                const short4 h4 = *(const short4*)(nfh + p * 128 + cs);
                const short4 l4 = *(const short4*)(nfl + p * 128 + cs);
                #pragma unroll
                for (int r = 0; r < 4; ++r) {
                    const float base = bf2f((unsigned short)h4[r]) + bf2f((unsigned short)l4[r]);
                    v[r] = fmaf(base, acc[i][j][r], base);      // base*(1+w)
                }
            } else {
                #pragma unroll
                for (int r = 0; r < 4; ++r) v[r] = fmaxf(acc[i][j][r], 0.f);
            }
            uint2 H, L;
            pack4(v, H, L);
            *(uint2*)(oh + p * LDCO + cs) = H;
            *(uint2*)(ol + p * LDCO + cs) = L;
        }
    }
}

// ---------------- fat-wave kernel: 64 pts / 256 thr / 4 waves / 48KB ----------------
template<bool DENSE>
__global__ __launch_bounds__(256, 3) void pointnet_sa(
    const float* __restrict__ xyz, const float* __restrict__ features,
    const float* __restrict__ new_xyz, const int* __restrict__ idx,
    const short* __restrict__ ws, const short* __restrict__ ftH, const short* __restrict__ ftL,
    const float* __restrict__ bg, const float* __restrict__ b1,
    const float* __restrict__ b2, const float* __restrict__ b3,
    float* __restrict__ out_pooled)  // (B, 256, P)
{
    __shared__ alignas(16) short smem[24576];      // 48 KB
    short* NFh = smem;                              // [64][128]
    short* NFl = smem + 8192;
    short* X0h = smem + 16384;                      // [64][64]
    short* X0l = smem + 20480;
    // X1 = NF cols 0-63 (stride 128); X2P = X0 region (stride 64); X2Q = NF cols 64-127

    const int tid = threadIdx.x, lane = tid & 63, wave = tid >> 6;   // wave 0..3
    const int q = lane >> 4, n16 = lane & 15;
    const int pt0 = blockIdx.x * 64;
    const int b = pt0 >> 16;

    if (DENSE) {
        // ---- gather: 4 threads/point, 4 chunk-pairs each, swizzled b128 stores ----
        const int gp = tid >> 2, gc = tid & 3;
        const int pt = pt0 + gp;
        const int n = idx[pt];
        const short* rH = ftH + ((size_t)b * kN + n) * 128;
        const short* rL = ftL + ((size_t)b * kN + n) * 128;
        uint4 h[4], l[4];
        #pragma unroll
        for (int k = 0; k < 4; ++k) {
            h[k] = *(const uint4*)(rH + (gc + 4 * k) * 8);
            l[k] = *(const uint4*)(rL + (gc + 4 * k) * 8);
        }
        if (gc == 0) {                              // merge xyz-diff into cols 0..2
            const float* xp = xyz + ((size_t)b * kN + n) * 3;
            const int pp = (pt >> 5) & (kP - 1);
            const float* np = new_xyz + ((size_t)b * kP + pp) * 3;
            union { uint4 u; short s[8]; } H, L;
            H.u = h[0]; L.u = l[0];
            #pragma unroll
            for (int c = 0; c < 3; ++c) {
                const float v = xp[c] - np[c];
                const unsigned short hh = f2bf(v);
                H.s[c] = (short)hh;
                L.s[c] = (short)f2bf(v - bf2f(hh));
            }
            h[0] = H.u; l[0] = L.u;
        }
        #pragma unroll
        for (int k = 0; k < 4; ++k) {
            const int sw = ((gc + 4 * k) ^ (gp & 7)) * 8;
            *(uint4*)(NFh + gp * 128 + sw) = h[k];
            *(uint4*)(NFl + gp * 128 + sw) = l[k];
        }
    } else {
        // ---- fallback: scalar gather, 4 col-groups/thread ----
        const int p = tid & 63;
        const int cg = tid >> 6;                    // 0..3
        const int pt = pt0 + p;
        const int n = idx[pt];
        const int pp = (pt >> 5) & (kP - 1);
        const float* fbp = features + (size_t)b * kC * kN + n;
        const float* xp = xyz + ((size_t)b * kN + n) * 3;
        const float* np = new_xyz + ((size_t)b * kP + pp) * 3;
        for (int c = cg; c < 128; c += 4) {
            float v;
            if (c < 3)        v = xp[c] - np[c];
            else if (c < 106) v = fbp[(size_t)(c - 3) * kN];
            else              v = 0.f;
            const unsigned short h = f2bf(v);
            const int cs = c ^ ((p & 7) << 3);
            NFh[p * 128 + cs] = (short)h;
            NFl[p * 128 + cs] = (short)f2bf(v - bf2f(h));
        }
    }
    __syncthreads();

    // ---- stage g: wave = o-tile, NPT=4 (all p-tiles) ----
    {
        f32x4 a[1][4];
        gemm_core<1, 4, 4, 128, 128, true>(NFh, NFl, ws + WG_HI, ws + WG_LO, bg, 0,
                                           wave, 0, lane, a);
        store_act<1, 4, true, 64>(a, X0h, X0l, NFh, NFl, wave, 0, lane);
    }
    __syncthreads();                               // B1: NF dead

    // ---- stage 1 -> X1 in NF cols 0-63 ----
    {
        f32x4 a[1][4];
        gemm_core<1, 4, 2, 64, 64, true>(X0h, X0l, ws + W1_HI, ws + W1_LO, b1, 0,
                                         wave, 0, lane, a);
        store_act<1, 4, false, 128>(a, NFh, NFl, nullptr, nullptr, wave, 0, lane);
    }
    __syncthreads();                               // B2: X0 dead

    // ---- stage 2: NOT=2 (o-tiles 2w,2w+1), NPT=4 -> X2 split ----
    {
        f32x4 a[2][4];
        gemm_core<2, 4, 2, 128, 64, true>(NFh, NFl, ws + W2_HI, ws + W2_LO, b2, 0,
                                          2 * wave, 0, lane, a);
        if (wave < 2)                               // o-tiles 0-3 -> X2P (X0 region)
            store_act<2, 4, false, 64>(a, X0h, X0l, nullptr, nullptr, 2 * wave, 0, lane);
        else                                        // o-tiles 4-7 -> X2Q (NF cols 64-127)
            store_act<2, 4, false, 128>(a, NFh + 64, NFl + 64, nullptr, nullptr,
                                        2 * wave - 4, 0, lane);
    }
    __syncthreads();                               // B3

    // ---- stage 3: NOT=4 (o-tiles 4w..4w+3), NPT=4; K over X2P then X2Q; pool ----
    {
        f32x4 a[4][4];
        gemm_core<4, 4, 2, 64, 128, true >(X0h, X0l, ws + W3_HI, ws + W3_LO, b3, 0,
                                           4 * wave, 0, lane, a);
        gemm_core<4, 4, 2, 128, 128, false>(NFh + 64, NFl + 64, ws + W3_HI, ws + W3_LO,
                                            nullptr, 64, 4 * wave, 0, lane, a);
        #pragma unroll
        for (int i = 0; i < 4; ++i) {
            #pragma unroll
            for (int sg = 0; sg < 2; ++sg) {
                #pragma unroll
                for (int r = 0; r < 4; ++r) {
                    float v = fmaxf(a[i][2 * sg][r], a[i][2 * sg + 1][r]);
                    v = fmaxf(v, __shfl_xor(v, 1, 16));
                    v = fmaxf(v, __shfl_xor(v, 2, 16));
                    v = fmaxf(v, __shfl_xor(v, 4, 16));
                    v = fmaxf(v, __shfl_xor(v, 8, 16));
                    v = fmaxf(v, 0.f);
                    if (n16 == 0) {
                        const int o = (4 * wave + i) * 16 + 4 * q + r;
                        const int g = (pt0 >> 5) + sg;                 // flat b*P + p
                        out_pooled[((size_t)(g >> 11) * 256 + o) * kP + (g & (kP - 1))] = v;
                    }
                }
            }
        }
    }
}
}  // namespace

extern "C" void kernel_launch(void* const* d_in, const int* in_sizes, int n_in,
                              void* d_out, int out_size, void* d_ws, size_t ws_size,
                              hipStream_t stream) {
    const float* xyz      = (const float*)d_in[0];
    const float* features = (const float*)d_in[1];
    const float* new_xyz  = (const float*)d_in[2];
    const int*   idx      = (const int*)d_in[3];
    const float* Wg = (const float*)d_in[4];
    const float* bg = (const float*)d_in[5];
    const float* W1 = (const float*)d_in[6];
    const float* b1 = (const float*)d_in[7];
    const float* W2 = (const float*)d_in[8];
    const float* b2 = (const float*)d_in[9];
    const float* W3 = (const float*)d_in[10];
    const float* b3 = (const float*)d_in[11];
    float* out = (float*)d_out;
    short* ws  = (short*)d_ws;
    short* ftH = (short*)((char*)d_ws + FT_OFF);
    short* ftL = ftH + FT_SHORTS;

    const int nxyz = kB * kP * 3;
    copy_newxyz<<<(nxyz + 255) / 256, 256, 0, stream>>>(new_xyz, out, nxyz);
    prep_weights<<<(53248 + 255) / 256, 256, 0, stream>>>(Wg, W1, W2, W3, ws);

    float* pooled = out + nxyz;
    if (ws_size >= WS_NEED) {
        prep_feat<<<kB * (kN / 64), 512, 0, stream>>>(features, ftH, ftL);
        pointnet_sa<true><<<(kB * kP * kS) / 64, 256, 0, stream>>>(
            xyz, features, new_xyz, idx, ws, ftH, ftL, bg, b1, b2, b3, pooled);
    } else {
        pointnet_sa<false><<<(kB * kP * kS) / 64, 256, 0, stream>>>(
            xyz, features, new_xyz, idx, ws, nullptr, nullptr, bg, b1, b2, b3, pooled);
    }
}

// Round 24
// 182.778 us; speedup vs baseline: 1.1357x; 1.1357x over previous
//
#include <hip/hip_runtime.h>
#include <stdint.h>

// PointNet SA via MFMA, v19 = v13 (best, 183.2us) with the gather moved to
// global_load_lds: linear LDS dest + XOR-pre-swizzled per-lane GLOBAL source
// (m173 pattern; XOR involutory -> byte-identical LDS layout to v13). Removes
// the VGPR round-trip + 4 swizzled ds_writes per thread from the gather phase.
// xyz patch via ds_write after explicit vmcnt(0) (same-wave ordering: point gp
// gathered and patched by wave gp>>3). Everything else identical to v13.

#define AS1 __attribute__((address_space(1)))
#define AS3 __attribute__((address_space(3)))

namespace {
constexpr int kB = 4, kN = 16384, kC = 103, kP = 2048, kS = 32;

using short8 = __attribute__((ext_vector_type(8))) short;
using short4 = __attribute__((ext_vector_type(4))) short;
using f32x4  = __attribute__((ext_vector_type(4))) float;

constexpr int WG_HI = 0,     WG_LO = 8192;     // 64 x 128
constexpr int W1_HI = 16384, W1_LO = 20480;    // 64 x 64
constexpr int W2_HI = 24576, W2_LO = 32768;    // 128 x 64
constexpr int W3_HI = 40960, W3_LO = 73728;    // 256 x 128
constexpr size_t FT_OFF    = 262144;
constexpr size_t FT_SHORTS = (size_t)kB * kN * 128;
constexpr size_t WS_NEED   = FT_OFF + 2 * FT_SHORTS * 2;

__device__ __forceinline__ unsigned short f2bf(float x) {
    unsigned u = __float_as_uint(x);
    u += 0x7fffu + ((u >> 16) & 1u);           // RNE
    return (unsigned short)(u >> 16);
}
__device__ __forceinline__ float bf2f(unsigned short h) {
    return __uint_as_float((unsigned)h << 16);
}
__device__ __forceinline__ unsigned cvtpk(float a, float b) {
    unsigned r;
    asm("v_cvt_pk_bf16_f32 %0, %1, %2" : "=v"(r) : "v"(a), "v"(b));
    return r;
}
__device__ __forceinline__ void pack4(const float v[4], uint2& H, uint2& L) {
    H.x = cvtpk(v[0], v[1]);
    H.y = cvtpk(v[2], v[3]);
    const float r0 = v[0] - __uint_as_float(H.x << 16);
    const float r1 = v[1] - __uint_as_float(H.x & 0xffff0000u);
    const float r2 = v[2] - __uint_as_float(H.y << 16);
    const float r3 = v[3] - __uint_as_float(H.y & 0xffff0000u);
    L.x = cvtpk(r0, r1);
    L.y = cvtpk(r2, r3);
}
__device__ __forceinline__ f32x4 mfma3(short8 ah, short8 al, short8 bh, short8 bl, f32x4 acc) {
    acc = __builtin_amdgcn_mfma_f32_16x16x32_bf16(ah, bh, acc, 0, 0, 0);
    acc = __builtin_amdgcn_mfma_f32_16x16x32_bf16(ah, bl, acc, 0, 0, 0);
    acc = __builtin_amdgcn_mfma_f32_16x16x32_bf16(al, bh, acc, 0, 0, 0);
    return acc;
}
__device__ __forceinline__ void glds16(const short* g, short* l) {
    __builtin_amdgcn_global_load_lds((const AS1 unsigned int*)g, (AS3 unsigned int*)l, 16, 0, 0);
}

__global__ void copy_newxyz(const float* __restrict__ src, float* __restrict__ dst, int n) {
    int i = blockIdx.x * blockDim.x + threadIdx.x;
    if (i < n) dst[i] = src[i];
}

__global__ void prep_weights(const float* __restrict__ Wg, const float* __restrict__ W1,
                             const float* __restrict__ W2, const float* __restrict__ W3,
                             short* __restrict__ ws) {
    int i = blockIdx.x * blockDim.x + threadIdx.x;
    if (i >= 53248) return;
    float w; int hi, lo, j;
    if (i < 8192)       { j = i;         int o = j >> 7, c = j & 127; w = (c < 106) ? Wg[o * 106 + c] : 0.f; hi = WG_HI; lo = WG_LO; }
    else if (i < 12288) { j = i - 8192;  int o = j >> 6, c = j & 63;  w = W1[o * 64 + c];  hi = W1_HI; lo = W1_LO; }
    else if (i < 20480) { j = i - 12288; int o = j >> 6, c = j & 63;  w = W2[o * 64 + c];  hi = W2_HI; lo = W2_LO; }
    else                { j = i - 20480; int o = j >> 7, c = j & 127; w = W3[o * 128 + c]; hi = W3_HI; lo = W3_LO; }
    unsigned short h = f2bf(w);
    ws[hi + j] = (short)h;
    ws[lo + j] = (short)f2bf(w - bf2f(h));
}

__global__ __launch_bounds__(512) void prep_feat(const float* __restrict__ f,
                                                 short* __restrict__ ftH, short* __restrict__ ftL) {
    __shared__ float tile[kC][65];
    const int bb = blockIdx.x >> 8;
    const int n0 = (blockIdx.x & 255) * 64;
    const int tid = threadIdx.x;
    for (int c = tid >> 6; c < kC; c += 8)
        tile[c][tid & 63] = f[((size_t)bb * kC + c) * kN + n0 + (tid & 63)];
    __syncthreads();
    const int np = tid >> 3, gc = tid & 7;
    short* rH = ftH + ((size_t)bb * kN + n0 + np) * 128;
    short* rL = ftL + ((size_t)bb * kN + n0 + np) * 128;
    #pragma unroll
    for (int kk = 0; kk < 2; ++kk) {
        const int chunk = gc + 8 * kk;
        union { uint4 u; short s[8]; } H, L;
        #pragma unroll
        for (int e = 0; e < 8; ++e) {
            const int col = chunk * 8 + e;
            float v = (col >= 3 && col < 106) ? tile[col - 3][np] : 0.f;
            unsigned short hh = f2bf(v);
            H.s[e] = (short)hh;
            L.s[e] = (short)f2bf(v - bf2f(hh));
        }
        *(uint4*)(rH + chunk * 8) = H.u;
        *(uint4*)(rL + chunk * 8) = L.u;
    }
}

// A: m=lane&15 (W row), k=8*(lane>>4)+j; B: n=lane&15 (point), same k; D: n=lane&15, m=4*(lane>>4)+r
template<int NOT, int NPT, int KT, int LDC, int LDW, bool INIT>
__device__ __forceinline__ void gemm_core(
    const short* __restrict__ xh, const short* __restrict__ xl,
    const short* __restrict__ wh, const short* __restrict__ wl,
    const float* __restrict__ bias, int kwoff,
    int ot0, int pt0t, int lane, f32x4 (&acc)[NOT][NPT])
{
    const int q = lane >> 4, n16 = lane & 15;
    if constexpr (INIT) {
        #pragma unroll
        for (int i = 0; i < NOT; ++i) {
            const f32x4 binit = *(const f32x4*)(bias + (ot0 + i) * 16 + 4 * q);
            #pragma unroll
            for (int j = 0; j < NPT; ++j) acc[i][j] = binit;
        }
    }
    #pragma unroll
    for (int kt = 0; kt < KT; ++kt) {
        const int k0 = kt * 32 + q * 8;
        short8 bh[NPT], bl[NPT];
        #pragma unroll
        for (int j = 0; j < NPT; ++j) {
            const int p = (pt0t + j) * 16 + n16;
            const int e = p * LDC + (k0 ^ ((p & 7) << 3));
            bh[j] = *(const short8*)(xh + e);
            bl[j] = *(const short8*)(xl + e);
        }
        #pragma unroll
        for (int i = 0; i < NOT; ++i) {
            const size_t we = (size_t)((ot0 + i) * 16 + n16) * LDW + kwoff + k0;
            const short8 ah = *(const short8*)(wh + we);
            const short8 al = *(const short8*)(wl + we);
            #pragma unroll
            for (int j = 0; j < NPT; ++j) acc[i][j] = mfma3(ah, al, bh[j], bl[j], acc[i][j]);
        }
    }
}

// GATE: v = base*(1+acc) with base from NF planes; else relu. cvt_pk packing.
template<int NOT, int NPT, bool GATE, int LDCO>
__device__ __forceinline__ void store_act(
    f32x4 (&acc)[NOT][NPT], short* __restrict__ oh, short* __restrict__ ol,
    const short* __restrict__ nfh, const short* __restrict__ nfl,
    int ot0, int pt0t, int lane)
{
    const int q = lane >> 4, n16 = lane & 15;
    #pragma unroll
    for (int i = 0; i < NOT; ++i) {
        const int ob = (ot0 + i) * 16 + 4 * q;
        #pragma unroll
        for (int j = 0; j < NPT; ++j) {
            const int p = (pt0t + j) * 16 + n16;
            const int cs = ob ^ ((p & 7) << 3);
            float v[4];
            if (GATE) {
                const short4 h4 = *(const short4*)(nfh + p * 128 + cs);
                const short4 l4 = *(const short4*)(nfl + p * 128 + cs);
                #pragma unroll
                for (int r = 0; r < 4; ++r) {
                    const float base = bf2f((unsigned short)h4[r]) + bf2f((unsigned short)l4[r]);
                    v[r] = fmaf(base, acc[i][j][r], base);      // base*(1+w)
                }
            } else {
                #pragma unroll
                for (int r = 0; r < 4; ++r) v[r] = fmaxf(acc[i][j][r], 0.f);
            }
            uint2 H, L;
            pack4(v, H, L);
            *(uint2*)(oh + p * LDCO + cs) = H;
            *(uint2*)(ol + p * LDCO + cs) = L;
        }
    }
}

template<bool DENSE>
__global__ __launch_bounds__(512, 2) void pointnet_sa(
    const float* __restrict__ xyz, const float* __restrict__ features,
    const float* __restrict__ new_xyz, const int* __restrict__ idx,
    const short* __restrict__ ws, const short* __restrict__ ftH, const short* __restrict__ ftL,
    const float* __restrict__ bg, const float* __restrict__ b1,
    const float* __restrict__ b2, const float* __restrict__ b3,
    float* __restrict__ out_pooled)  // (B, 256, P)
{
    __shared__ alignas(16) short smem[24576];      // 48 KB
    short* NFh = smem;                              // [64][128]
    short* NFl = smem + 8192;
    short* X0h = smem + 16384;                      // [64][64]
    short* X0l = smem + 20480;
    // X1 = NF cols 0-63 (stride 128); X2P = X0 region (stride 64); X2Q = NF cols 64-127

    const int tid = threadIdx.x, lane = tid & 63, wave = tid >> 6;
    const int q = lane >> 4, n16 = lane & 15;
    const int pt0 = blockIdx.x * 64;
    const int b = pt0 >> 16;

    if (DENSE) {
        // ---- glds gather: wave handles 8 pts; 2 calls/plane x 4 pts/call ----
        // LDS dest linear (base + lane*16B); swizzle baked into GLOBAL source:
        // dest chunk d of point gp receives source chunk d ^ (gp & 7)  (involution
        // => LDS layout byte-identical to v13's write-side swizzle).
        const int l16 = lane >> 4;                 // point-in-quad 0..3
        const int c16 = lane & 15;                 // dest chunk 0..15
        #pragma unroll
        for (int cg = 0; cg < 2; ++cg) {
            const int gp = wave * 8 + cg * 4 + l16;
            const int pt = pt0 + gp;
            const int n = idx[pt];
            const size_t row = ((size_t)b * kN + n) * 128;
            const int sc = (c16 ^ (gp & 7)) * 8;   // pre-swizzled source chunk
            const int lbase = __builtin_amdgcn_readfirstlane((wave * 8 + cg * 4) * 128);
            glds16(ftH + row + sc, smem + lbase);              // -> NFh rows
            glds16(ftL + row + sc, smem + 8192 + lbase);       // -> NFl rows
        }
        // xyz-diff values (global loads overlap the glds stream)
        float xd0 = 0.f, xd1 = 0.f, xd2 = 0.f;
        if ((lane & 7) == 0) {
            const int gp = wave * 8 + (lane >> 3);
            const int pt = pt0 + gp;
            const int n = idx[pt];
            const float* xp = xyz + ((size_t)b * kN + n) * 3;
            const int pp = (pt >> 5) & (kP - 1);
            const float* np = new_xyz + ((size_t)b * kP + pp) * 3;
            xd0 = xp[0] - np[0]; xd1 = xp[1] - np[1]; xd2 = xp[2] - np[2];
        }
        asm volatile("s_waitcnt vmcnt(0)" ::: "memory");       // glds + xyz landed
        if ((lane & 7) == 0) {                      // patch cols 0-2 (same wave as glds)
            const int gp = wave * 8 + (lane >> 3);
            const int o = gp * 128 + (gp & 7) * 8;  // source chunk 0 lives at dest chunk gp&7
            const unsigned short h0 = f2bf(xd0), h1 = f2bf(xd1), h2 = f2bf(xd2);
            NFh[o + 0] = (short)h0; NFh[o + 1] = (short)h1; NFh[o + 2] = (short)h2;
            NFl[o + 0] = (short)f2bf(xd0 - bf2f(h0));
            NFl[o + 1] = (short)f2bf(xd1 - bf2f(h1));
            NFl[o + 2] = (short)f2bf(xd2 - bf2f(h2));
        }
    } else {
        // ---- fallback: scalar gather from original features layout ----
        const int p = tid & 63;
        const int cg = tid >> 6;
        const int pt = pt0 + p;
        const int n = idx[pt];
        const int pp = (pt >> 5) & (kP - 1);
        const float* fbp = features + (size_t)b * kC * kN + n;
        const float* xp = xyz + ((size_t)b * kN + n) * 3;
        const float* np = new_xyz + ((size_t)b * kP + pp) * 3;
        for (int c = cg; c < 128; c += 8) {
            float v;
            if (c < 3)        v = xp[c] - np[c];
            else if (c < 106) v = fbp[(size_t)(c - 3) * kN];
            else              v = 0.f;
            const unsigned short h = f2bf(v);
            const int cs = c ^ ((p & 7) << 3);
            NFh[p * 128 + cs] = (short)h;
            NFl[p * 128 + cs] = (short)f2bf(v - bf2f(h));
        }
    }
    __syncthreads();

    // ---- stage g ----
    {
        f32x4 a[1][2];
        gemm_core<1, 2, 4, 128, 128, true>(NFh, NFl, ws + WG_HI, ws + WG_LO, bg, 0,
                                           wave & 3, 2 * (wave >> 2), lane, a);
        store_act<1, 2, true, 64>(a, X0h, X0l, NFh, NFl, wave & 3, 2 * (wave >> 2), lane);
    }
    __syncthreads();                               // B1: NF dead

    // ---- stage 1 -> X1 in NF cols 0-63 ----
    {
        f32x4 a[1][2];
        gemm_core<1, 2, 2, 64, 64, true>(X0h, X0l, ws + W1_HI, ws + W1_LO, b1, 0,
                                         wave & 3, 2 * (wave >> 2), lane, a);
        store_act<1, 2, false, 128>(a, NFh, NFl, nullptr, nullptr,
                                    wave & 3, 2 * (wave >> 2), lane);
    }
    __syncthreads();                               // B2: X0 dead

    // ---- stage 2 -> X2 split ----
    {
        f32x4 a[2][2];
        gemm_core<2, 2, 2, 128, 64, true>(NFh, NFl, ws + W2_HI, ws + W2_LO, b2, 0,
                                          2 * (wave & 3), 2 * (wave >> 2), lane, a);
        if ((wave & 3) < 2)
            store_act<2, 2, false, 64>(a, X0h, X0l, nullptr, nullptr,
                                       2 * (wave & 3), 2 * (wave >> 2), lane);
        else
            store_act<2, 2, false, 128>(a, NFh + 64, NFl + 64, nullptr, nullptr,
                                        (2 * (wave & 3)) & 3, 2 * (wave >> 2), lane);
    }
    __syncthreads();                               // B3

    // ---- stage 3: K over X2P then X2Q + pool ----
    {
        f32x4 a[2][4];
        gemm_core<2, 4, 2, 64, 128, true >(X0h, X0l, ws + W3_HI, ws + W3_LO, b3, 0,
                                           2 * wave, 0, lane, a);
        gemm_core<2, 4, 2, 128, 128, false>(NFh + 64, NFl + 64, ws + W3_HI, ws + W3_LO,
                                            nullptr, 64, 2 * wave, 0, lane, a);
        #pragma unroll
        for (int i = 0; i < 2; ++i) {
            #pragma unroll
            for (int sg = 0; sg < 2; ++sg) {
                #pragma unroll
                for (int r = 0; r < 4; ++r) {
                    float v = fmaxf(a[i][2 * sg][r], a[i][2 * sg + 1][r]);
                    v = fmaxf(v, __shfl_xor(v, 1, 16));
                    v = fmaxf(v, __shfl_xor(v, 2, 16));
                    v = fmaxf(v, __shfl_xor(v, 4, 16));
                    v = fmaxf(v, __shfl_xor(v, 8, 16));
                    v = fmaxf(v, 0.f);
                    if (n16 == 0) {
                        const int o = (2 * wave + i) * 16 + 4 * q + r;
                        const int g = (pt0 >> 5) + sg;
                        out_pooled[((size_t)(g >> 11) * 256 + o) * kP + (g & (kP - 1))] = v;
                    }
                }
            }
        }
    }
}
}  // namespace

extern "C" void kernel_launch(void* const* d_in, const int* in_sizes, int n_in,
                              void* d_out, int out_size, void* d_ws, size_t ws_size,
                              hipStream_t stream) {
    const float* xyz      = (const float*)d_in[0];
    const float* features = (const float*)d_in[1];
    const float* new_xyz  = (const float*)d_in[2];
    const int*   idx      = (const int*)d_in[3];
    const float* Wg = (const float*)d_in[4];
    const float* bg = (const float*)d_in[5];
    const float* W1 = (const float*)d_in[6];
    const float* b1 = (const float*)d_in[7];
    const float* W2 = (const float*)d_in[8];
    const float* b2 = (const float*)d_in[9];
    const float* W3 = (const float*)d_in[10];
    const float* b3 = (const float*)d_in[11];
    float* out = (float*)d_out;
    short* ws  = (short*)d_ws;
    short* ftH = (short*)((char*)d_ws + FT_OFF);
    short* ftL = ftH + FT_SHORTS;

    const int nxyz = kB * kP * 3;
    copy_newxyz<<<(nxyz + 255) / 256, 256, 0, stream>>>(new_xyz, out, nxyz);
    prep_weights<<<(53248 + 255) / 256, 256, 0, stream>>>(Wg, W1, W2, W3, ws);

    float* pooled = out + nxyz;
    if (ws_size >= WS_NEED) {
        prep_feat<<<kB * (kN / 64), 512, 0, stream>>>(features, ftH, ftL);
        pointnet_sa<true><<<(kB * kP * kS) / 64, 512, 0, stream>>>(
            xyz, features, new_xyz, idx, ws, ftH, ftL, bg, b1, b2, b3, pooled);
    } else {
        pointnet_sa<false><<<(kB * kP * kS) / 64, 512, 0, stream>>>(
            xyz, features, new_xyz, idx, ws, nullptr, nullptr, bg, b1, b2, b3, pooled);
    }
}